// Round 13
// baseline (92.088 us; speedup 1.0000x reference)
//
#include <hip/hip_runtime.h>

#define EPS 1e-6f
#define J 24

// ---- setup kernel: fold SH constants into 28 floats/joint in d_ws ----
// layout per joint j (28 floats, 16B-aligned since 28*4=112=7*16):
//  [0..11]  T rows 0..2
//  [12..14] loc
//  [15]     f0 = C0*F0 + 0.5
//  [16..18] cx, cy, cz
//  [19..21] cxy, cyz, cxz
//  [22..24] gxx, gyy, gzz
//  [25..27] pad
__global__ void fold_kernel(const float* __restrict__ transforms,
                            const float* __restrict__ sh_feats,
                            const float* __restrict__ locs,
                            float* __restrict__ cj)
{
    const int j = threadIdx.x;
    if (j >= J) return;

    float F[9];
    #pragma unroll
    for (int k = 0; k < 9; ++k) F[k] = sh_feats[j * 9 + k];

    const float C0  = 0.28209479177387814f;
    const float C1  = 0.4886025119029199f;
    const float C2a = 1.0925484305920792f;

    const float f0  = C0 * F[0] + 0.5f;
    const float cy  = -C1 * F[1];
    const float cz  =  C1 * F[2];
    const float cx  = -C1 * F[3];
    const float cxy =  C2a * F[4];
    const float cyz = -C2a * F[5];
    const float c6  = 0.31539156525252005f * F[6];
    const float cxz = -C2a * F[7];
    const float c8  = 0.5462742152960396f  * F[8];

    float* s = cj + j * 28;
    #pragma unroll
    for (int k = 0; k < 12; ++k) s[k] = transforms[j * 16 + k];
    s[12] = locs[j * 3 + 0];
    s[13] = locs[j * 3 + 1];
    s[14] = locs[j * 3 + 2];
    s[15] = f0;
    s[16] = cx;  s[17] = cy;  s[18] = cz;
    s[19] = cxy; s[20] = cyz; s[21] = cxz;
    s[22] = c8 - c6;          // gxx
    s[23] = -c6 - c8;         // gyy
    s[24] = 2.0f * c6;        // gzz
    s[25] = 0.f; s[26] = 0.f; s[27] = 0.f;
}

// ---- main kernel: joint constants via wave-uniform scalar loads (no LDS) ----
__global__ __launch_bounds__(256, 8) void shcaster_kernel(
    const float* __restrict__ xyz,
    const float* __restrict__ vdir,
    const float* __restrict__ cj,     // folded constants in d_ws
    float* __restrict__ out,
    int n)
{
    const int i = blockIdx.x * blockDim.x + threadIdx.x;
    if (i >= n) return;

    const float px = xyz[3 * i + 0];
    const float py = xyz[3 * i + 1];
    const float pz = xyz[3 * i + 2];
    const float vx = vdir[3 * i + 0];
    const float vy = vdir[3 * i + 1];
    const float vz = vdir[3 * i + 2];

    float wsum = 0.f;
    float Ta[12];
    #pragma unroll
    for (int k = 0; k < 12; ++k) Ta[k] = 0.f;

    #pragma unroll
    for (int j = 0; j < J; ++j) {
        const float* s = cj + j * 28;   // compile-time offset -> s_load (uniform)

        // pts = T @ [p,1]
        const float ax = fmaf(s[0], px, fmaf(s[1], py, fmaf(s[2],  pz, s[3])));
        const float ay = fmaf(s[4], px, fmaf(s[5], py, fmaf(s[6],  pz, s[7])));
        const float az = fmaf(s[8], px, fmaf(s[9], py, fmaf(s[10], pz, s[11])));

        // vd = loc - pts
        const float dx = s[12] - ax;
        const float dy = s[13] - ay;
        const float dz = s[14] - az;
        const float d2 = fmaf(dx, dx, fmaf(dy, dy, dz * dz));

        const float inv_n = __builtin_amdgcn_rsqf(fmaxf(d2, 1e-24f));
        const float len = d2 * inv_n;              // = sqrt(d2)
        const float nx = dx * inv_n;
        const float ny = dy * inv_n;
        const float nz = dz * inv_n;

        // rads = relu(SH(n) . feats + 0.5), constants pre-folded
        float rads = s[15];
        rads = fmaf(s[16], nx, rads);
        rads = fmaf(s[17], ny, rads);
        rads = fmaf(s[18], nz, rads);
        rads = fmaf(s[19], nx * ny, rads);
        rads = fmaf(s[20], ny * nz, rads);
        rads = fmaf(s[21], nx * nz, rads);
        rads = fmaf(s[22], nx * nx, rads);
        rads = fmaf(s[23], ny * ny, rads);
        rads = fmaf(s[24], nz * nz, rads);
        rads = fmaxf(rads, 0.f);

        float rel = fmaxf(1.f - len * __builtin_amdgcn_rcpf(fmaxf(rads, EPS)), 0.f);
        rel = (rads < EPS) ? 0.f : rel;

        wsum += rel;
        Ta[0]  = fmaf(rel, s[0],  Ta[0]);
        Ta[1]  = fmaf(rel, s[1],  Ta[1]);
        Ta[2]  = fmaf(rel, s[2],  Ta[2]);
        Ta[3]  = fmaf(rel, s[3],  Ta[3]);
        Ta[4]  = fmaf(rel, s[4],  Ta[4]);
        Ta[5]  = fmaf(rel, s[5],  Ta[5]);
        Ta[6]  = fmaf(rel, s[6],  Ta[6]);
        Ta[7]  = fmaf(rel, s[7],  Ta[7]);
        Ta[8]  = fmaf(rel, s[8],  Ta[8]);
        Ta[9]  = fmaf(rel, s[9],  Ta[9]);
        Ta[10] = fmaf(rel, s[10], Ta[10]);
        Ta[11] = fmaf(rel, s[11], Ta[11]);
    }

    const float inv_w = __builtin_amdgcn_rcpf(fmaxf(wsum, EPS));
    const bool valid = wsum > EPS;

    const float axo = fmaf(Ta[0], px, fmaf(Ta[1], py, fmaf(Ta[2],  pz, Ta[3])))  * inv_w;
    const float ayo = fmaf(Ta[4], px, fmaf(Ta[5], py, fmaf(Ta[6],  pz, Ta[7])))  * inv_w;
    const float azo = fmaf(Ta[8], px, fmaf(Ta[9], py, fmaf(Ta[10], pz, Ta[11]))) * inv_w;

    const float qx = px - vx;
    const float qy = py - vy;
    const float qz = pz - vz;
    const float bxo = fmaf(Ta[0], qx, fmaf(Ta[1], qy, fmaf(Ta[2],  qz, Ta[3])))  * inv_w;
    const float byo = fmaf(Ta[4], qx, fmaf(Ta[5], qy, fmaf(Ta[6],  qz, Ta[7])))  * inv_w;
    const float bzo = fmaf(Ta[8], qx, fmaf(Ta[9], qy, fmaf(Ta[10], qz, Ta[11]))) * inv_w;

    const float ox = valid ? axo : px;
    const float oy = valid ? ayo : py;
    const float oz = valid ? azo : pz;
    const float wx = ox - (valid ? bxo : qx);
    const float wy = oy - (valid ? byo : qy);
    const float wz = oz - (valid ? bzo : qz);

    out[3 * i + 0] = ox;
    out[3 * i + 1] = oy;
    out[3 * i + 2] = oz;
    float* out2 = out + (size_t)3 * n;
    out2[3 * i + 0] = wx;
    out2[3 * i + 1] = wy;
    out2[3 * i + 2] = wz;
}

extern "C" void kernel_launch(void* const* d_in, const int* in_sizes, int n_in,
                              void* d_out, int out_size, void* d_ws, size_t ws_size,
                              hipStream_t stream) {
    const int n = (out_size > 0) ? (out_size / 6) : 524288;
    const int big = 3 * n;

    const float* xyz  = nullptr;
    const float* vdir = nullptr;
    const float* trf  = nullptr;
    const float* shf  = nullptr;
    const float* locs = nullptr;
    int bigSeen = 0;
    for (int k = 0; k < n_in; ++k) {
        const int s = in_sizes[k];
        if (s == big) {
            if (bigSeen++ == 0) xyz = (const float*)d_in[k];
            else                vdir = (const float*)d_in[k];
        } else if (s == 384) {
            trf = (const float*)d_in[k];
        } else if (s == 216) {
            shf = (const float*)d_in[k];
        } else if (s == 72) {
            locs = (const float*)d_in[k];
        }
    }
    if (!xyz || !vdir || !trf || !shf || !locs) {
        xyz  = (const float*)d_in[0];
        vdir = (const float*)d_in[1];
        trf  = (const float*)d_in[2];
        shf  = (const float*)d_in[n_in >= 6 ? 4 : 3];
        locs = (const float*)d_in[n_in >= 6 ? 5 : 4];
    }

    float* cj = (float*)d_ws;          // 24*28*4 = 2688 B of the workspace
    float* out = (float*)d_out;

    fold_kernel<<<1, 64, 0, stream>>>(trf, shf, locs, cj);

    const int block = 256;
    const int grid = (n + block - 1) / block;
    shcaster_kernel<<<grid, block, 0, stream>>>(xyz, vdir, cj, out, n);
}

// Round 14
// 89.748 us; speedup vs baseline: 1.0261x; 1.0261x over previous
//
#include <hip/hip_runtime.h>

#define EPS 1e-6f
#define J 24
#define NPAIR 12
#define PAIR_STRIDE 56   // floats per joint-pair block (28 v2f, 224 B)

typedef float v2f __attribute__((ext_vector_type(2)));

__device__ __forceinline__ v2f fma2(v2f a, v2f b, v2f c) {
    return __builtin_elementwise_fma(a, b, c);
}
__device__ __forceinline__ v2f max2(v2f a, v2f b) {
    return __builtin_elementwise_max(a, b);
}

// ---- setup kernel: fold SH constants, pair-interleaved SoA in d_ws ----
// pair pp (joints 2pp, 2pp+1), element k in [0,25): cj[pp*56 + 2k + (j&1)]
//  k 0..11  T rows 0..2
//  k 12..14 loc
//  k 15     f0 = C0*F0 + 0.5
//  k 16..18 cx, cy, cz
//  k 19..21 cxy, cyz, cxz
//  k 22..24 gxx, gyy, gzz
__global__ void fold_kernel(const float* __restrict__ transforms,
                            const float* __restrict__ sh_feats,
                            const float* __restrict__ locs,
                            float* __restrict__ cj)
{
    const int j = threadIdx.x;
    if (j >= J) return;

    float F[9];
    #pragma unroll
    for (int k = 0; k < 9; ++k) F[k] = sh_feats[j * 9 + k];

    const float C0  = 0.28209479177387814f;
    const float C1  = 0.4886025119029199f;
    const float C2a = 1.0925484305920792f;

    const float f0  = C0 * F[0] + 0.5f;
    const float cy  = -C1 * F[1];
    const float cz  =  C1 * F[2];
    const float cx  = -C1 * F[3];
    const float cxy =  C2a * F[4];
    const float cyz = -C2a * F[5];
    const float c6  = 0.31539156525252005f * F[6];
    const float cxz = -C2a * F[7];
    const float c8  = 0.5462742152960396f  * F[8];

    float vals[25];
    #pragma unroll
    for (int k = 0; k < 12; ++k) vals[k] = transforms[j * 16 + k];
    vals[12] = locs[j * 3 + 0];
    vals[13] = locs[j * 3 + 1];
    vals[14] = locs[j * 3 + 2];
    vals[15] = f0;
    vals[16] = cx;  vals[17] = cy;  vals[18] = cz;
    vals[19] = cxy; vals[20] = cyz; vals[21] = cxz;
    vals[22] = c8 - c6;
    vals[23] = -c6 - c8;
    vals[24] = 2.0f * c6;

    float* base = cj + (j >> 1) * PAIR_STRIDE + (j & 1);
    #pragma unroll
    for (int k = 0; k < 25; ++k) base[2 * k] = vals[k];
}

// ---- main kernel: two joints per iteration via packed fp32 (v_pk_fma_f32) ----
__global__ __launch_bounds__(256, 8) void shcaster_kernel(
    const float* __restrict__ xyz,
    const float* __restrict__ vdir,
    const float* __restrict__ cj,
    float* __restrict__ out,
    int n)
{
    const int i = blockIdx.x * blockDim.x + threadIdx.x;
    if (i >= n) return;

    const float px = xyz[3 * i + 0];
    const float py = xyz[3 * i + 1];
    const float pz = xyz[3 * i + 2];
    const float vx = vdir[3 * i + 0];
    const float vy = vdir[3 * i + 1];
    const float vz = vdir[3 * i + 2];

    const v2f px2 = {px, px};
    const v2f py2 = {py, py};
    const v2f pz2 = {pz, pz};
    const v2f one2  = {1.f, 1.f};
    const v2f zero2 = {0.f, 0.f};

    v2f wsum2 = zero2;
    v2f Ta2[12];
    #pragma unroll
    for (int k = 0; k < 12; ++k) Ta2[k] = zero2;

    #pragma unroll 4
    for (int pp = 0; pp < NPAIR; ++pp) {
        const v2f* s = (const v2f*)(cj + pp * PAIR_STRIDE);  // uniform loads

        // pts = T @ [p,1], two joints at once
        const v2f ax = fma2(s[0], px2, fma2(s[1], py2, fma2(s[2],  pz2, s[3])));
        const v2f ay = fma2(s[4], px2, fma2(s[5], py2, fma2(s[6],  pz2, s[7])));
        const v2f az = fma2(s[8], px2, fma2(s[9], py2, fma2(s[10], pz2, s[11])));

        // vd = loc - pts
        const v2f dx = s[12] - ax;
        const v2f dy = s[13] - ay;
        const v2f dz = s[14] - az;
        v2f d2 = fma2(dx, dx, fma2(dy, dy, dz * dz));
        d2 = max2(d2, (v2f){1e-24f, 1e-24f});

        const v2f inv = {__builtin_amdgcn_rsqf(d2.x), __builtin_amdgcn_rsqf(d2.y)};
        const v2f len = d2 * inv;
        const v2f nx = dx * inv;
        const v2f ny = dy * inv;
        const v2f nz = dz * inv;

        // rads = relu(SH(n).F + 0.5), folded constants
        v2f rads = s[15];
        rads = fma2(s[16], nx, rads);
        rads = fma2(s[17], ny, rads);
        rads = fma2(s[18], nz, rads);
        rads = fma2(s[19], nx * ny, rads);
        rads = fma2(s[20], ny * nz, rads);
        rads = fma2(s[21], nx * nz, rads);
        rads = fma2(s[22], nx * nx, rads);
        rads = fma2(s[23], ny * ny, rads);
        rads = fma2(s[24], nz * nz, rads);
        rads = max2(rads, zero2);

        const v2f rc = {__builtin_amdgcn_rcpf(fmaxf(rads.x, EPS)),
                        __builtin_amdgcn_rcpf(fmaxf(rads.y, EPS))};
        v2f rel = max2(fma2(-len, rc, one2), zero2);
        rel.x = (rads.x < EPS) ? 0.f : rel.x;
        rel.y = (rads.y < EPS) ? 0.f : rel.y;

        wsum2 += rel;
        Ta2[0]  = fma2(rel, s[0],  Ta2[0]);
        Ta2[1]  = fma2(rel, s[1],  Ta2[1]);
        Ta2[2]  = fma2(rel, s[2],  Ta2[2]);
        Ta2[3]  = fma2(rel, s[3],  Ta2[3]);
        Ta2[4]  = fma2(rel, s[4],  Ta2[4]);
        Ta2[5]  = fma2(rel, s[5],  Ta2[5]);
        Ta2[6]  = fma2(rel, s[6],  Ta2[6]);
        Ta2[7]  = fma2(rel, s[7],  Ta2[7]);
        Ta2[8]  = fma2(rel, s[8],  Ta2[8]);
        Ta2[9]  = fma2(rel, s[9],  Ta2[9]);
        Ta2[10] = fma2(rel, s[10], Ta2[10]);
        Ta2[11] = fma2(rel, s[11], Ta2[11]);
    }

    // lane-pair reduction
    const float wsum = wsum2.x + wsum2.y;
    float Ta[12];
    #pragma unroll
    for (int k = 0; k < 12; ++k) Ta[k] = Ta2[k].x + Ta2[k].y;

    const float inv_w = __builtin_amdgcn_rcpf(fmaxf(wsum, EPS));
    const bool valid = wsum > EPS;

    const float axo = fmaf(Ta[0], px, fmaf(Ta[1], py, fmaf(Ta[2],  pz, Ta[3])))  * inv_w;
    const float ayo = fmaf(Ta[4], px, fmaf(Ta[5], py, fmaf(Ta[6],  pz, Ta[7])))  * inv_w;
    const float azo = fmaf(Ta[8], px, fmaf(Ta[9], py, fmaf(Ta[10], pz, Ta[11]))) * inv_w;

    const float qx = px - vx;
    const float qy = py - vy;
    const float qz = pz - vz;
    const float bxo = fmaf(Ta[0], qx, fmaf(Ta[1], qy, fmaf(Ta[2],  qz, Ta[3])))  * inv_w;
    const float byo = fmaf(Ta[4], qx, fmaf(Ta[5], qy, fmaf(Ta[6],  qz, Ta[7])))  * inv_w;
    const float bzo = fmaf(Ta[8], qx, fmaf(Ta[9], qy, fmaf(Ta[10], qz, Ta[11]))) * inv_w;

    const float ox = valid ? axo : px;
    const float oy = valid ? ayo : py;
    const float oz = valid ? azo : pz;
    const float wx = ox - (valid ? bxo : qx);
    const float wy = oy - (valid ? byo : qy);
    const float wz = oz - (valid ? bzo : qz);

    out[3 * i + 0] = ox;
    out[3 * i + 1] = oy;
    out[3 * i + 2] = oz;
    float* out2 = out + (size_t)3 * n;
    out2[3 * i + 0] = wx;
    out2[3 * i + 1] = wy;
    out2[3 * i + 2] = wz;
}

extern "C" void kernel_launch(void* const* d_in, const int* in_sizes, int n_in,
                              void* d_out, int out_size, void* d_ws, size_t ws_size,
                              hipStream_t stream) {
    const int n = (out_size > 0) ? (out_size / 6) : 524288;
    const int big = 3 * n;

    const float* xyz  = nullptr;
    const float* vdir = nullptr;
    const float* trf  = nullptr;
    const float* shf  = nullptr;
    const float* locs = nullptr;
    int bigSeen = 0;
    for (int k = 0; k < n_in; ++k) {
        const int s = in_sizes[k];
        if (s == big) {
            if (bigSeen++ == 0) xyz = (const float*)d_in[k];
            else                vdir = (const float*)d_in[k];
        } else if (s == 384) {
            trf = (const float*)d_in[k];
        } else if (s == 216) {
            shf = (const float*)d_in[k];
        } else if (s == 72) {
            locs = (const float*)d_in[k];
        }
    }
    if (!xyz || !vdir || !trf || !shf || !locs) {
        xyz  = (const float*)d_in[0];
        vdir = (const float*)d_in[1];
        trf  = (const float*)d_in[2];
        shf  = (const float*)d_in[n_in >= 6 ? 4 : 3];
        locs = (const float*)d_in[n_in >= 6 ? 5 : 4];
    }

    float* cj = (float*)d_ws;          // 12 pairs * 56 floats = 2688 B
    float* out = (float*)d_out;

    fold_kernel<<<1, 64, 0, stream>>>(trf, shf, locs, cj);

    const int block = 256;
    const int grid = (n + block - 1) / block;
    shcaster_kernel<<<grid, block, 0, stream>>>(xyz, vdir, cj, out, n);
}

// Round 15
// 89.359 us; speedup vs baseline: 1.0305x; 1.0043x over previous
//
#include <hip/hip_runtime.h>

#define EPS 1e-6f
#define J 24
#define NPAIR 12
#define PAIR_STRIDE 56   // floats per joint-pair block (28 v2f, 224 B)

typedef float v2f __attribute__((ext_vector_type(2)));

__device__ __forceinline__ v2f fma2(v2f a, v2f b, v2f c) {
    return __builtin_elementwise_fma(a, b, c);
}
__device__ __forceinline__ v2f max2(v2f a, v2f b) {
    return __builtin_elementwise_max(a, b);
}

// ---- setup kernel: fold SH constants, pair-interleaved SoA in d_ws ----
// pair pp (joints 2pp, 2pp+1), element k in [0,25): cj[pp*56 + 2k + (j&1)]
//  k 0..11  T rows 0..2 | k 12..14 loc | k 15 f0 | k 16..18 cx,cy,cz
//  k 19..21 cxy,cyz,cxz | k 22..24 gxx,gyy,gzz
__global__ void fold_kernel(const float* __restrict__ transforms,
                            const float* __restrict__ sh_feats,
                            const float* __restrict__ locs,
                            float* __restrict__ cj)
{
    const int j = threadIdx.x;
    if (j >= J) return;

    float F[9];
    #pragma unroll
    for (int k = 0; k < 9; ++k) F[k] = sh_feats[j * 9 + k];

    const float C0  = 0.28209479177387814f;
    const float C1  = 0.4886025119029199f;
    const float C2a = 1.0925484305920792f;

    const float f0  = C0 * F[0] + 0.5f;
    const float cy  = -C1 * F[1];
    const float cz  =  C1 * F[2];
    const float cx  = -C1 * F[3];
    const float cxy =  C2a * F[4];
    const float cyz = -C2a * F[5];
    const float c6  = 0.31539156525252005f * F[6];
    const float cxz = -C2a * F[7];
    const float c8  = 0.5462742152960396f  * F[8];

    float vals[25];
    #pragma unroll
    for (int k = 0; k < 12; ++k) vals[k] = transforms[j * 16 + k];
    vals[12] = locs[j * 3 + 0];
    vals[13] = locs[j * 3 + 1];
    vals[14] = locs[j * 3 + 2];
    vals[15] = f0;
    vals[16] = cx;  vals[17] = cy;  vals[18] = cz;
    vals[19] = cxy; vals[20] = cyz; vals[21] = cxz;
    vals[22] = c8 - c6;
    vals[23] = -c6 - c8;
    vals[24] = 2.0f * c6;

    float* base = cj + (j >> 1) * PAIR_STRIDE + (j & 1);
    #pragma unroll
    for (int k = 0; k < 25; ++k) base[2 * k] = vals[k];
}

struct PState {
    float px, py, pz;
    v2f wsum2;
    v2f Ta2[12];
};

__device__ __forceinline__ void joint_pair(const v2f* __restrict__ s, PState& st) {
    const v2f px2 = {st.px, st.px};
    const v2f py2 = {st.py, st.py};
    const v2f pz2 = {st.pz, st.pz};
    const v2f one2  = {1.f, 1.f};
    const v2f zero2 = {0.f, 0.f};

    const v2f ax = fma2(s[0], px2, fma2(s[1], py2, fma2(s[2],  pz2, s[3])));
    const v2f ay = fma2(s[4], px2, fma2(s[5], py2, fma2(s[6],  pz2, s[7])));
    const v2f az = fma2(s[8], px2, fma2(s[9], py2, fma2(s[10], pz2, s[11])));

    const v2f dx = s[12] - ax;
    const v2f dy = s[13] - ay;
    const v2f dz = s[14] - az;
    v2f d2 = fma2(dx, dx, fma2(dy, dy, dz * dz));
    d2 = max2(d2, (v2f){1e-24f, 1e-24f});

    const v2f inv = {__builtin_amdgcn_rsqf(d2.x), __builtin_amdgcn_rsqf(d2.y)};
    const v2f len = d2 * inv;
    const v2f nx = dx * inv;
    const v2f ny = dy * inv;
    const v2f nz = dz * inv;

    // rads: tree-shaped to cut dependent latency
    v2f r0 = fma2(s[16], nx, s[15]);
    r0 = fma2(s[19], nx * ny, r0);
    r0 = fma2(s[22], nx * nx, r0);
    v2f r1 = fma2(s[17], ny, zero2);
    r1 = fma2(s[20], ny * nz, r1);
    r1 = fma2(s[23], ny * ny, r1);
    v2f r2 = fma2(s[18], nz, zero2);
    r2 = fma2(s[21], nx * nz, r2);
    r2 = fma2(s[24], nz * nz, r2);
    v2f rads = (r0 + r1) + r2;
    rads = max2(rads, zero2);

    const v2f rc = {__builtin_amdgcn_rcpf(fmaxf(rads.x, EPS)),
                    __builtin_amdgcn_rcpf(fmaxf(rads.y, EPS))};
    v2f rel = max2(fma2(-len, rc, one2), zero2);
    rel.x = (rads.x < EPS) ? 0.f : rel.x;
    rel.y = (rads.y < EPS) ? 0.f : rel.y;

    st.wsum2 += rel;
    #pragma unroll
    for (int k = 0; k < 12; ++k) st.Ta2[k] = fma2(rel, s[k], st.Ta2[k]);
}

__device__ __forceinline__ void finish_store(const PState& st,
                                             float vx, float vy, float vz,
                                             float* __restrict__ out,
                                             float* __restrict__ out2, int i) {
    const float wsum = st.wsum2.x + st.wsum2.y;
    float Ta[12];
    #pragma unroll
    for (int k = 0; k < 12; ++k) Ta[k] = st.Ta2[k].x + st.Ta2[k].y;

    const float inv_w = __builtin_amdgcn_rcpf(fmaxf(wsum, EPS));
    const bool valid = wsum > EPS;
    const float px = st.px, py = st.py, pz = st.pz;

    const float axo = fmaf(Ta[0], px, fmaf(Ta[1], py, fmaf(Ta[2],  pz, Ta[3])))  * inv_w;
    const float ayo = fmaf(Ta[4], px, fmaf(Ta[5], py, fmaf(Ta[6],  pz, Ta[7])))  * inv_w;
    const float azo = fmaf(Ta[8], px, fmaf(Ta[9], py, fmaf(Ta[10], pz, Ta[11]))) * inv_w;

    const float qx = px - vx;
    const float qy = py - vy;
    const float qz = pz - vz;
    const float bxo = fmaf(Ta[0], qx, fmaf(Ta[1], qy, fmaf(Ta[2],  qz, Ta[3])))  * inv_w;
    const float byo = fmaf(Ta[4], qx, fmaf(Ta[5], qy, fmaf(Ta[6],  qz, Ta[7])))  * inv_w;
    const float bzo = fmaf(Ta[8], qx, fmaf(Ta[9], qy, fmaf(Ta[10], qz, Ta[11]))) * inv_w;

    const float ox = valid ? axo : px;
    const float oy = valid ? ayo : py;
    const float oz = valid ? azo : pz;
    const float wx = ox - (valid ? bxo : qx);
    const float wy = oy - (valid ? byo : qy);
    const float wz = oz - (valid ? bzo : qz);

    out[3 * i + 0] = ox;
    out[3 * i + 1] = oy;
    out[3 * i + 2] = oz;
    out2[3 * i + 0] = wx;
    out2[3 * i + 1] = wy;
    out2[3 * i + 2] = wz;
}

// ---- main kernel: 2 points per thread x 2 joints per iteration ----
__global__ __launch_bounds__(256, 4) void shcaster_kernel(
    const float* __restrict__ xyz,
    const float* __restrict__ vdir,
    const float* __restrict__ cj,
    float* __restrict__ out,
    int n)
{
    const int n2 = n >> 1;
    const int g = blockIdx.x * blockDim.x + threadIdx.x;
    if (g >= n2) return;
    const int ia = g;
    const int ib = g + n2;

    PState A, B;
    A.px = xyz[3 * ia + 0]; A.py = xyz[3 * ia + 1]; A.pz = xyz[3 * ia + 2];
    B.px = xyz[3 * ib + 0]; B.py = xyz[3 * ib + 1]; B.pz = xyz[3 * ib + 2];
    A.wsum2 = (v2f){0.f, 0.f};
    B.wsum2 = (v2f){0.f, 0.f};
    #pragma unroll
    for (int k = 0; k < 12; ++k) { A.Ta2[k] = (v2f){0.f, 0.f}; B.Ta2[k] = (v2f){0.f, 0.f}; }

    #pragma unroll 2
    for (int pp = 0; pp < NPAIR; ++pp) {
        const v2f* s = (const v2f*)(cj + pp * PAIR_STRIDE);  // wave-uniform
        joint_pair(s, A);
        joint_pair(s, B);
    }

    const float vxa = vdir[3 * ia + 0], vya = vdir[3 * ia + 1], vza = vdir[3 * ia + 2];
    const float vxb = vdir[3 * ib + 0], vyb = vdir[3 * ib + 1], vzb = vdir[3 * ib + 2];

    float* out2 = out + (size_t)3 * n;
    finish_store(A, vxa, vya, vza, out, out2, ia);
    finish_store(B, vxb, vyb, vzb, out, out2, ib);
}

extern "C" void kernel_launch(void* const* d_in, const int* in_sizes, int n_in,
                              void* d_out, int out_size, void* d_ws, size_t ws_size,
                              hipStream_t stream) {
    const int n = (out_size > 0) ? (out_size / 6) : 524288;
    const int big = 3 * n;

    const float* xyz  = nullptr;
    const float* vdir = nullptr;
    const float* trf  = nullptr;
    const float* shf  = nullptr;
    const float* locs = nullptr;
    int bigSeen = 0;
    for (int k = 0; k < n_in; ++k) {
        const int s = in_sizes[k];
        if (s == big) {
            if (bigSeen++ == 0) xyz = (const float*)d_in[k];
            else                vdir = (const float*)d_in[k];
        } else if (s == 384) {
            trf = (const float*)d_in[k];
        } else if (s == 216) {
            shf = (const float*)d_in[k];
        } else if (s == 72) {
            locs = (const float*)d_in[k];
        }
    }
    if (!xyz || !vdir || !trf || !shf || !locs) {
        xyz  = (const float*)d_in[0];
        vdir = (const float*)d_in[1];
        trf  = (const float*)d_in[2];
        shf  = (const float*)d_in[n_in >= 6 ? 4 : 3];
        locs = (const float*)d_in[n_in >= 6 ? 5 : 4];
    }

    float* cj = (float*)d_ws;          // 12 pairs * 56 floats = 2688 B
    float* out = (float*)d_out;

    fold_kernel<<<1, 64, 0, stream>>>(trf, shf, locs, cj);

    const int n2 = n >> 1;
    const int block = 256;
    const int grid = (n2 + block - 1) / block;
    shcaster_kernel<<<grid, block, 0, stream>>>(xyz, vdir, cj, out, n);
}

// Round 16
// 87.015 us; speedup vs baseline: 1.0583x; 1.0269x over previous
//
#include <hip/hip_runtime.h>

#define EPS 1e-6f
#define J 24
#define NPAIR 12
#define PAIR_STRIDE 56   // floats per joint-pair block (28 v2f, 224 B, 16B-aligned)

typedef float v2f __attribute__((ext_vector_type(2)));

__device__ __forceinline__ v2f fma2(v2f a, v2f b, v2f c) {
    return __builtin_elementwise_fma(a, b, c);
}
__device__ __forceinline__ v2f max2(v2f a, v2f b) {
    return __builtin_elementwise_max(a, b);
}

// ---- setup: fold constants, pair-interleaved SoA in d_ws ----
// element k of joint j: cj[(j>>1)*56 + 2k + (j&1)]
//  k 0..11  T rows 0..2 (for Ta accumulation + u's R part)
//  k 12..14 tml = T translation - loc   (u = R.p + tml)
//  k 15     f0 = C0*F0 + 0.5
//  k 16..18 cx, cy, cz                  (rads uses -(c.u)*inv)
//  k 19..21 cxy, cyz, cxz
//  k 22..24 gxx, gyy, gzz
__global__ void fold_kernel(const float* __restrict__ transforms,
                            const float* __restrict__ sh_feats,
                            const float* __restrict__ locs,
                            float* __restrict__ cj)
{
    const int j = threadIdx.x;
    if (j >= J) return;

    float F[9];
    #pragma unroll
    for (int k = 0; k < 9; ++k) F[k] = sh_feats[j * 9 + k];

    const float C0  = 0.28209479177387814f;
    const float C1  = 0.4886025119029199f;
    const float C2a = 1.0925484305920792f;

    const float f0  = C0 * F[0] + 0.5f;
    const float cy  = -C1 * F[1];
    const float cz  =  C1 * F[2];
    const float cx  = -C1 * F[3];
    const float cxy =  C2a * F[4];
    const float cyz = -C2a * F[5];
    const float c6  = 0.31539156525252005f * F[6];
    const float cxz = -C2a * F[7];
    const float c8  = 0.5462742152960396f  * F[8];

    float vals[25];
    #pragma unroll
    for (int k = 0; k < 12; ++k) vals[k] = transforms[j * 16 + k];
    vals[12] = vals[3]  - locs[j * 3 + 0];   // tml_x
    vals[13] = vals[7]  - locs[j * 3 + 1];   // tml_y
    vals[14] = vals[11] - locs[j * 3 + 2];   // tml_z
    vals[15] = f0;
    vals[16] = cx;  vals[17] = cy;  vals[18] = cz;
    vals[19] = cxy; vals[20] = cyz; vals[21] = cxz;
    vals[22] = c8 - c6;       // gxx
    vals[23] = -c6 - c8;      // gyy
    vals[24] = 2.0f * c6;     // gzz

    float* base = cj + (j >> 1) * PAIR_STRIDE + (j & 1);
    #pragma unroll
    for (int k = 0; k < 25; ++k) base[2 * k] = vals[k];
}

// ---- main: 1 point/thread, 2 joints/iter, no-normalize rads form ----
__global__ __launch_bounds__(256, 6) void shcaster_kernel(
    const float* __restrict__ xyz,
    const float* __restrict__ vdir,
    const float* __restrict__ cj,
    float* __restrict__ out,
    int n)
{
    const int i = blockIdx.x * blockDim.x + threadIdx.x;
    if (i >= n) return;

    const float px = xyz[3 * i + 0];
    const float py = xyz[3 * i + 1];
    const float pz = xyz[3 * i + 2];
    const float vx = vdir[3 * i + 0];   // load early; used in epilogue
    const float vy = vdir[3 * i + 1];
    const float vz = vdir[3 * i + 2];

    const v2f px2 = {px, px};
    const v2f py2 = {py, py};
    const v2f pz2 = {pz, pz};
    const v2f one2  = {1.f, 1.f};
    const v2f zero2 = {0.f, 0.f};
    const v2f eps2  = {EPS, EPS};

    v2f wsum2 = zero2;
    v2f Ta2[12];
    #pragma unroll
    for (int k = 0; k < 12; ++k) Ta2[k] = zero2;

    #pragma unroll 2
    for (int pp = 0; pp < NPAIR; ++pp) {
        const v2f* s = (const v2f*)(cj + pp * PAIR_STRIDE);  // wave-uniform s_load

        // u = R.p + (t - loc)   — vd = -u; d2, quad, |u| all even in u
        const v2f ux = fma2(s[0], px2, fma2(s[1], py2, fma2(s[2],  pz2, s[12])));
        const v2f uy = fma2(s[4], px2, fma2(s[5], py2, fma2(s[6],  pz2, s[13])));
        const v2f uz = fma2(s[8], px2, fma2(s[9], py2, fma2(s[10], pz2, s[14])));

        const v2f xx = ux * ux;
        const v2f yy = uy * uy;
        const v2f zz = uz * uz;
        v2f d2 = (xx + yy) + zz;
        d2 = max2(d2, (v2f){1e-24f, 1e-24f});

        // rsq kicks off now; lin/quad evaluate in parallel with its latency
        const v2f inv = {__builtin_amdgcn_rsqf(d2.x), __builtin_amdgcn_rsqf(d2.y)};

        // lin = c.u ; quad = quadratic form in u (normalization deferred)
        v2f lin = fma2(s[16], ux, fma2(s[17], uy, s[18] * uz));
        v2f quad = fma2(s[19], ux * uy, fma2(s[20], uy * uz, fma2(s[21], ux * uz,
                   fma2(s[22], xx, fma2(s[23], yy, s[24] * zz)))));

        const v2f len  = d2 * inv;        // = |u|
        const v2f inv2 = inv * inv;       // = 1/d2

        // rads = f0 - lin*inv + quad*inv2   (vd = -u flips the linear term)
        v2f rads = fma2(quad, inv2, s[15]);
        rads = fma2(-lin, inv, rads);
        rads = max2(rads, zero2);

        const v2f rm = max2(rads, eps2);
        const v2f rc = {__builtin_amdgcn_rcpf(rm.x), __builtin_amdgcn_rcpf(rm.y)};
        v2f rel = max2(fma2(-len, rc, one2), zero2);
        rel.x = (rads.x < EPS) ? 0.f : rel.x;
        rel.y = (rads.y < EPS) ? 0.f : rel.y;

        wsum2 += rel;
        #pragma unroll
        for (int k = 0; k < 12; ++k) Ta2[k] = fma2(rel, s[k], Ta2[k]);
    }

    const float wsum = wsum2.x + wsum2.y;
    float Ta[12];
    #pragma unroll
    for (int k = 0; k < 12; ++k) Ta[k] = Ta2[k].x + Ta2[k].y;

    const float inv_w = __builtin_amdgcn_rcpf(fmaxf(wsum, EPS));
    const bool valid = wsum > EPS;

    const float axo = fmaf(Ta[0], px, fmaf(Ta[1], py, fmaf(Ta[2],  pz, Ta[3])))  * inv_w;
    const float ayo = fmaf(Ta[4], px, fmaf(Ta[5], py, fmaf(Ta[6],  pz, Ta[7])))  * inv_w;
    const float azo = fmaf(Ta[8], px, fmaf(Ta[9], py, fmaf(Ta[10], pz, Ta[11]))) * inv_w;

    const float qx = px - vx;
    const float qy = py - vy;
    const float qz = pz - vz;
    const float bxo = fmaf(Ta[0], qx, fmaf(Ta[1], qy, fmaf(Ta[2],  qz, Ta[3])))  * inv_w;
    const float byo = fmaf(Ta[4], qx, fmaf(Ta[5], qy, fmaf(Ta[6],  qz, Ta[7])))  * inv_w;
    const float bzo = fmaf(Ta[8], qx, fmaf(Ta[9], qy, fmaf(Ta[10], qz, Ta[11]))) * inv_w;

    const float ox = valid ? axo : px;
    const float oy = valid ? ayo : py;
    const float oz = valid ? azo : pz;
    const float wx = ox - (valid ? bxo : qx);
    const float wy = oy - (valid ? byo : qy);
    const float wz = oz - (valid ? bzo : qz);

    out[3 * i + 0] = ox;
    out[3 * i + 1] = oy;
    out[3 * i + 2] = oz;
    float* out2 = out + (size_t)3 * n;
    out2[3 * i + 0] = wx;
    out2[3 * i + 1] = wy;
    out2[3 * i + 2] = wz;
}

extern "C" void kernel_launch(void* const* d_in, const int* in_sizes, int n_in,
                              void* d_out, int out_size, void* d_ws, size_t ws_size,
                              hipStream_t stream) {
    const int n = (out_size > 0) ? (out_size / 6) : 524288;
    const int big = 3 * n;

    const float* xyz  = nullptr;
    const float* vdir = nullptr;
    const float* trf  = nullptr;
    const float* shf  = nullptr;
    const float* locs = nullptr;
    int bigSeen = 0;
    for (int k = 0; k < n_in; ++k) {
        const int s = in_sizes[k];
        if (s == big) {
            if (bigSeen++ == 0) xyz = (const float*)d_in[k];
            else                vdir = (const float*)d_in[k];
        } else if (s == 384) {
            trf = (const float*)d_in[k];
        } else if (s == 216) {
            shf = (const float*)d_in[k];
        } else if (s == 72) {
            locs = (const float*)d_in[k];
        }
    }
    if (!xyz || !vdir || !trf || !shf || !locs) {
        xyz  = (const float*)d_in[0];
        vdir = (const float*)d_in[1];
        trf  = (const float*)d_in[2];
        shf  = (const float*)d_in[n_in >= 6 ? 4 : 3];
        locs = (const float*)d_in[n_in >= 6 ? 5 : 4];
    }

    float* cj = (float*)d_ws;          // 12 pairs * 56 floats = 2688 B
    float* out = (float*)d_out;

    fold_kernel<<<1, 64, 0, stream>>>(trf, shf, locs, cj);

    const int block = 256;
    const int grid = (n + block - 1) / block;
    shcaster_kernel<<<grid, block, 0, stream>>>(xyz, vdir, cj, out, n);
}